// Round 2
// baseline (654.977 us; speedup 1.0000x reference)
//
#include <hip/hip_runtime.h>
#include <cstdint>

typedef __attribute__((ext_vector_type(8))) short short8;
typedef __attribute__((ext_vector_type(4))) short short4v;
typedef __attribute__((ext_vector_type(4))) float f32x4;

__device__ inline unsigned short f2bf(float f) {
    union { float f; unsigned int u; } v; v.f = f;
    unsigned int r = v.u + 0x7FFFu + ((v.u >> 16) & 1u);   // round-to-nearest-even
    return (unsigned short)(r >> 16);
}

// 16x16x16 bf16 MFMA: A[m=l15][k=4q+t], B[k=4q+t][n=l15], D[m=4q+r][n=l15]
__device__ inline f32x4 mfma16(short4v a4, short4v b4, f32x4 c) {
#if __has_builtin(__builtin_amdgcn_mfma_f32_16x16x16bf16_1k)
    return __builtin_amdgcn_mfma_f32_16x16x16bf16_1k(a4, b4, c, 0, 0, 0);
#else
    asm volatile("v_mfma_f32_16x16x16_bf16 %0, %1, %2, %0\n\t"
                 "s_nop 7\n\ts_nop 7"
                 : "+v"(c) : "v"(a4), "v"(b4));
    return c;
#endif
}

// Prep: Wt[d][k] = bf16(W[k][d]);  W is [256][128] row-major.  64 KB output in d_ws.
__global__ void wprep_kernel(const float* __restrict__ W, unsigned short* __restrict__ wt) {
    int idx = blockIdx.x * 256 + threadIdx.x;     // 0..32767
    int k = idx >> 7, d = idx & 127;
    wt[d * 256 + k] = f2bf(W[idx]);
}

// Fully register-resident GAT: no LDS, no __syncthreads, waves independent.
// Each wave owns 2 batches (2 batch-aligned 16-row MFMA tiles: rows 0..11 real, 12..15 pad).
__global__ __launch_bounds__(256, 4)
void gat_kernel(const float* __restrict__ x, const float* __restrict__ adj,
                const unsigned short* __restrict__ wt, const float* __restrict__ a,
                float* __restrict__ out) {
    const int tid  = threadIdx.x;
    const int wave = tid >> 6, lane = tid & 63;
    const int l15  = lane & 15, quad = lane >> 4;

    const int bat0 = blockIdx.x * 8 + wave * 2;          // 2 batches per wave
    const int rrow = (l15 < 12) ? l15 : 11;              // pad lanes duplicate row 11

    const float* xp0 = x + ((long)bat0 * 12 + rrow) * 256 + quad * 8;
    const float* xp1 = xp0 + 12 * 256;
    // B-frag needs B[k = quad*8 + j][n = l15]  ->  bake quad*8 into the W base too.
    const unsigned short* wp = wt + (long)l15 * 256 + quad * 8;

    // ---- phase 1: H = x @ W via bf16 MFMA.  A = x rows (m=row), B = Wt (n=d).
    // acc[bt][dt][r] = H[row = 4*quad + r][d = dt*16 + l15]  (f32)
    f32x4 acc[2][8];
#pragma unroll
    for (int bt = 0; bt < 2; ++bt)
#pragma unroll
        for (int dt = 0; dt < 8; ++dt)
            acc[bt][dt] = f32x4{0.f, 0.f, 0.f, 0.f};

#pragma unroll
    for (int kt = 0; kt < 8; ++kt) {
        const int k0 = kt * 32;                          // lane covers k0+quad*8 .. +7 via ptr
        f32x4 lo0 = *(const f32x4*)(xp0 + k0);
        f32x4 hi0 = *(const f32x4*)(xp0 + k0 + 4);
        f32x4 lo1 = *(const f32x4*)(xp1 + k0);
        f32x4 hi1 = *(const f32x4*)(xp1 + k0 + 4);
        short8 xf0, xf1;
        xf0[0] = (short)f2bf(lo0[0]); xf0[1] = (short)f2bf(lo0[1]);
        xf0[2] = (short)f2bf(lo0[2]); xf0[3] = (short)f2bf(lo0[3]);
        xf0[4] = (short)f2bf(hi0[0]); xf0[5] = (short)f2bf(hi0[1]);
        xf0[6] = (short)f2bf(hi0[2]); xf0[7] = (short)f2bf(hi0[3]);
        xf1[0] = (short)f2bf(lo1[0]); xf1[1] = (short)f2bf(lo1[1]);
        xf1[2] = (short)f2bf(lo1[2]); xf1[3] = (short)f2bf(lo1[3]);
        xf1[4] = (short)f2bf(hi1[0]); xf1[5] = (short)f2bf(hi1[1]);
        xf1[6] = (short)f2bf(hi1[2]); xf1[7] = (short)f2bf(hi1[3]);
#pragma unroll
        for (int dt = 0; dt < 8; ++dt) {
            short8 wf = *(const short8*)(wp + dt * 16 * 256 + k0);
            acc[0][dt] = __builtin_amdgcn_mfma_f32_16x16x32_bf16(xf0, wf, acc[0][dt], 0, 0, 0);
            acc[1][dt] = __builtin_amdgcn_mfma_f32_16x16x32_bf16(xf1, wf, acc[1][dt], 0, 0, 0);
        }
    }

    // ---- phase 2a: s_j = H.a_lo, s_i = H.a_hi  (f32 H straight from acc) ----
    float aLoR[8], aHiR[8];
#pragma unroll
    for (int dt = 0; dt < 8; ++dt) {
        aLoR[dt] = a[dt * 16 + l15];
        aHiR[dt] = a[128 + dt * 16 + l15];
    }
    float sjv[2][4], siv[2][4];
#pragma unroll
    for (int bt = 0; bt < 2; ++bt)
#pragma unroll
        for (int r = 0; r < 4; ++r) {
            float sj = 0.f, si = 0.f;
#pragma unroll
            for (int dt = 0; dt < 8; ++dt) {
                float h = acc[bt][dt][r];
                sj += h * aLoR[dt];
                si += h * aHiR[dt];
            }
            // reduce over the 16 d-lanes (same quad group)
#pragma unroll
            for (int m = 1; m <= 8; m <<= 1) {
                sj += __shfl_xor(sj, m, 64);
                si += __shfl_xor(si, m, 64);
            }
            sjv[bt][r] = sj;                 // s_j for row 4*quad+r of batch bt
            siv[bt][r] = si;
        }

    // adj row for this lane: i = l15, cols 4*quad .. 4*quad+3 (clamped pads unused)
    const int ar  = (l15 < 12) ? l15 : 11;
    const int acq = (quad < 3) ? quad : 2;
    const f32x4 adjv = *(const f32x4*)(adj + ar * 12 + acq * 4);
    const int bpidx = (((l15 >> 2) << 4) + l15) << 2;    // byte idx: pull from quad (l15>>2)

    // ---- phase 2b+3 per batch: softmax -> alpha A-frag; h' = alpha @ H via MFMA ----
#pragma unroll
    for (int bt = 0; bt < 2; ++bt) {
        // distribute si: lane needs s_i of row i = l15 (held by quad l15>>2, reg l15&3)
        float bp0 = __int_as_float(__builtin_amdgcn_ds_bpermute(bpidx, __float_as_int(siv[bt][0])));
        float bp1 = __int_as_float(__builtin_amdgcn_ds_bpermute(bpidx, __float_as_int(siv[bt][1])));
        float bp2 = __int_as_float(__builtin_amdgcn_ds_bpermute(bpidx, __float_as_int(siv[bt][2])));
        float bp3 = __int_as_float(__builtin_amdgcn_ds_bpermute(bpidx, __float_as_int(siv[bt][3])));
        float s01 = (l15 & 1) ? bp1 : bp0;
        float s23 = (l15 & 1) ? bp3 : bp2;
        float si_i = (l15 & 2) ? s23 : s01;

        // unnormalized p[t] = exp(leaky_relu(si + sj)) masked; no max-sub (|z| <~ 4)
        float p[4]; float rs = 0.f;
        const bool rowok = (l15 < 12) && (quad < 3);
#pragma unroll
        for (int t = 0; t < 4; ++t) {
            float z = si_i + sjv[bt][t];
            z = z > 0.f ? z : 0.2f * z;                  // leaky_relu(0.2)
            bool ok = rowok && (adjv[t] == 1.0f);
            p[t] = ok ? __expf(z) : 0.f;
            rs += p[t];
        }
        rs += __shfl_xor(rs, 16, 64);                    // reduce over quads (j groups)
        rs += __shfl_xor(rs, 32, 64);
        float inv = rs > 0.f ? 1.0f / rs : 0.f;

        short4v af;                                      // A[m=l15][k=4q+t] = alpha[i][j]
#pragma unroll
        for (int t = 0; t < 4; ++t) af[t] = (short)f2bf(p[t] * inv);

        const long ob = (long)(bat0 + bt) * 12 * 128;
#pragma unroll
        for (int dt = 0; dt < 8; ++dt) {
            f32x4 h = acc[bt][dt];
            short4v bf;                                  // B[k=4q+t][n=l15] = H[j][d] = acc!
            bf[0] = (short)f2bf(h[0]); bf[1] = (short)f2bf(h[1]);
            bf[2] = (short)f2bf(h[2]); bf[3] = (short)f2bf(h[3]);
            f32x4 o = mfma16(af, bf, f32x4{0.f, 0.f, 0.f, 0.f});
            if (quad < 3) {                              // rows 4q+r, valid i < 12
#pragma unroll
                for (int r = 0; r < 4; ++r) {
                    float v = o[r];
                    v = v > 0.f ? v : (__expf(v) - 1.0f);   // ELU
                    out[ob + (quad * 4 + r) * 128 + dt * 16 + l15] = v;
                }
            }
        }
    }
}

extern "C" void kernel_launch(void* const* d_in, const int* in_sizes, int n_in,
                              void* d_out, int out_size, void* d_ws, size_t ws_size,
                              hipStream_t stream) {
    const float* x   = (const float*)d_in[0];   // [32768,12,256]
    const float* adj = (const float*)d_in[1];   // [12,12]
    const float* W   = (const float*)d_in[2];   // [256,128]
    const float* a   = (const float*)d_in[3];   // [256,1]
    float* out = (float*)d_out;                 // [32768,12,128]
    unsigned short* wt = (unsigned short*)d_ws; // 64 KB bf16 W^T

    hipLaunchKernelGGL(wprep_kernel, dim3(128), dim3(256), 0, stream, W, wt);
    hipLaunchKernelGGL(gat_kernel, dim3(4096), dim3(256), 0, stream, x, adj, wt, a, out);
}